// Round 17
// baseline (38.201 us; speedup 1.0000x reference)
//
#include <hip/hip_runtime.h>

// Fixed-shape problem
#define NBATCH 4
#define NPTS   8192
#define MTGT   8192
#define BN     (NBATCH*NPTS)      // 32768 sources (== total targets)
#define NCHUNK 8                  // target chunks per batch (1024 targets each)
#define SGRP   32                 // source groups per batch (256 sources each)
// grid: (32, 8, 4) = 1024 blocks of 256 threads (4 waves)

typedef __attribute__((ext_vector_type(8)))  short bf16x8;   // guide-verified frag type
typedef __attribute__((ext_vector_type(16))) float f32x16;

__device__ __forceinline__ unsigned short f2bf(float x) {   // RNE fp32->bf16
    unsigned u = __float_as_uint(x);
    return (unsigned short)((u + 0x7fffu + ((u >> 16) & 1u)) >> 16);
}
__device__ __forceinline__ float bf2f(unsigned short h) {
    return __uint_as_float(((unsigned)h) << 16);
}

// Pack A (sources, scaled by -2, hi/lo split) and B (targets hi/lo + ||t||^2
// 3-way split) into MFMA fragment order (slot pairing validated: R13-R16
// absmax 0.0). Also zeroes the reduce completion counter each call.
__global__ __launch_bounds__(256) void prep_kernel(const float* __restrict__ src,
                                                   const float* __restrict__ tgt,
                                                   unsigned short* __restrict__ Apk,
                                                   unsigned short* __restrict__ Bpk,
                                                   unsigned* __restrict__ counter) {
    const int i = blockIdx.x * 256 + threadIdx.x;   // 0..BN-1
    const int T = i >> 5, l = i & 31;
    const unsigned ONE = 0x3F80u;
    if (i == 0) *counter = 0u;

    // ---- A: a = -2*s
    float sx = src[3*(size_t)i], sy = src[3*(size_t)i+1], sz = src[3*(size_t)i+2];
    float axf = -2.f*sx, ayf = -2.f*sy, azf = -2.f*sz;
    unsigned axh = f2bf(axf), ayh = f2bf(ayf), azh = f2bf(azf);
    unsigned axl = f2bf(axf - bf2f(axh));
    unsigned ayl = f2bf(ayf - bf2f(ayh));
    unsigned azl = f2bf(azf - bf2f(azh));
    uint4* a0 = (uint4*)(Apk + ((size_t)T*64 +      l) * 8);
    uint4* a1 = (uint4*)(Apk + ((size_t)T*64 + 32 + l) * 8);
    *a0 = make_uint4(axh | (ayh<<16), azh | (axl<<16), ayl | (azl<<16), axh | (ayh<<16));
    *a1 = make_uint4(azh | (ONE<<16), ONE | (ONE<<16), 0u, 0u);

    // ---- B: t hi/lo + tsq 3-split (invalid target -> tsq = 1e30)
    float tx = tgt[3*(size_t)i], ty = tgt[3*(size_t)i+1], tz = tgt[3*(size_t)i+2];
    unsigned txh = f2bf(tx), tyh = f2bf(ty), tzh = f2bf(tz);
    unsigned txl = f2bf(tx - bf2f(txh));
    unsigned tyl = f2bf(ty - bf2f(tyh));
    unsigned tzl = f2bf(tz - bf2f(tzh));
    float tsq = fmaf(tx, tx, fmaf(ty, ty, tz * tz));
    bool valid = (tx != 0.f) || (ty != 0.f) || (tz != 0.f);
    unsigned qh, qm, ql;
    if (valid) {
        qh = f2bf(tsq);
        float r1 = tsq - bf2f(qh); qm = f2bf(r1);
        float r2 = r1 - bf2f(qm);  ql = f2bf(r2);
    } else { qh = f2bf(1e30f); qm = 0u; ql = 0u; }
    uint4* b0 = (uint4*)(Bpk + ((size_t)T*64 +      l) * 8);
    uint4* b1 = (uint4*)(Bpk + ((size_t)T*64 + 32 + l) * 8);
    *b0 = make_uint4(txh | (tyh<<16), tzh | (txh<<16), tyh | (tzh<<16), txl | (tyl<<16));
    *b1 = make_uint4(tzl | (qh<<16), qm | (ql<<16), 0u, 0u);
}

// R14's EXACT nn kernel (fastest proven): rows = sources, cols = targets,
// 4 independent MFMAs + 32 INDEPENDENT v_min3 per iteration (16 acc elems
// per strip = full ILP), shuffle reduction once per block in the epilogue.
__global__ __launch_bounds__(256, 4) void nn_mfma_kernel(const unsigned short* __restrict__ Apk,
                                                         const unsigned short* __restrict__ Bpk,
                                                         float* __restrict__ wspart) {
    const int lane = threadIdx.x & 63, wid = threadIdx.x >> 6;
    const int sg = blockIdx.x, cy = blockIdx.y, bz = blockIdx.z;

    const bf16x8* Ap = (const bf16x8*)Apk;
    const bf16x8* Bp = (const bf16x8*)Bpk;

    const int Ts0 = bz * 256 + sg * 8 + wid * 2;      // source tile (32 rows) base
    bf16x8 a0 = Ap[(size_t)Ts0 * 64 + lane];
    bf16x8 a1 = Ap[(size_t)(Ts0 + 1) * 64 + lane];

    f32x16 z, bm0, bm1;
#pragma unroll
    for (int e = 0; e < 16; ++e) { z[e] = 0.f; bm0[e] = 3e38f; bm1[e] = 3e38f; }

    const int Tb0 = bz * 256 + cy * 32;               // target tile base for chunk
    const bf16x8* bp = Bp + (size_t)Tb0 * 64 + lane;

#pragma unroll 2
    for (int m = 0; m < 32; m += 2) {
        bf16x8 bfA = bp[(size_t)m * 64];              // 16B/lane coalesced; L1-shared
        bf16x8 bfB = bp[(size_t)(m + 1) * 64];
        f32x16 d0A = __builtin_amdgcn_mfma_f32_32x32x16_bf16(a0, bfA, z, 0, 0, 0);
        f32x16 d0B = __builtin_amdgcn_mfma_f32_32x32x16_bf16(a0, bfB, z, 0, 0, 0);
        f32x16 d1A = __builtin_amdgcn_mfma_f32_32x32x16_bf16(a1, bfA, z, 0, 0, 0);
        f32x16 d1B = __builtin_amdgcn_mfma_f32_32x32x16_bf16(a1, bfB, z, 0, 0, 0);
#pragma unroll
        for (int e = 0; e < 16; ++e) {
            bm0[e] = fminf(fminf(d0A[e], d0B[e]), bm0[e]);   // -> v_min3_f32
            bm1[e] = fminf(fminf(d1A[e], d1B[e]), bm1[e]);
        }
    }

    // cross-lane min over the 32 cols (xor masks <32 stay within each half)
#pragma unroll
    for (int e = 0; e < 16; ++e) {
        float v0 = bm0[e], v1 = bm1[e];
#pragma unroll
        for (int off = 16; off > 0; off >>= 1) {
            v0 = fminf(v0, __shfl_xor(v0, off));
            v1 = fminf(v1, __shfl_xor(v1, off));
        }
        bm0[e] = v0; bm1[e] = v1;
    }

    // writer lanes 0 (h=0) and 32 (h=1). C/D map (m74/m101 verified):
    // row = (reg&3) + 8*(reg>>2) + 4*(lane>>5)  -> reg 4q+e covers rows 8q+4h+e
    if ((lane & 31) == 0) {
        const int h = lane >> 5;
        float* wb = wspart + (size_t)cy * BN + (size_t)bz * NPTS + sg * 256 + wid * 64 + 4 * h;
#pragma unroll
        for (int q = 0; q < 4; ++q) {
            *(float4*)(wb + 8 * q)      = make_float4(bm0[4*q], bm0[4*q+1], bm0[4*q+2], bm0[4*q+3]);
            *(float4*)(wb + 8 * q + 32) = make_float4(bm1[4*q], bm1[4*q+1], bm1[4*q+2], bm1[4*q+3]);
        }
    }
}

// 128 blocks x 256: min over 8 chunk-partials (coalesced), + ||s||^2, validity,
// fixed-order double partials; LAST block (completion counter) does the final
// combine with PARALLEL atomic loads + fixed LDS tree (proven R16).
__global__ __launch_bounds__(256) void reduce_kernel(const float* __restrict__ src,
                                                     const float* __restrict__ wspart,
                                                     double* __restrict__ partials,
                                                     unsigned* __restrict__ counter,
                                                     float* __restrict__ out) {
    const int blk = blockIdx.x, tid = threadIdx.x;
    const int gid = blk * 256 + tid;

    float m = 3e38f;
#pragma unroll
    for (int c = 0; c < NCHUNK; ++c) m = fminf(m, wspart[(size_t)c * BN + gid]);

    float sx = src[3*(size_t)gid], sy = src[3*(size_t)gid+1], sz = src[3*(size_t)gid+2];
    bool valid = (sx != 0.f) || (sy != 0.f) || (sz != 0.f);
    float ssq = fmaf(sx, sx, fmaf(sy, sy, sz * sz));
    float sq = fmaxf(0.f, ssq + m);

    __shared__ double sh[512];
    sh[tid] = valid ? (double)sq : 0.0;
    sh[256 + tid] = valid ? 1.0 : 0.0;
    __syncthreads();
    for (int s = 128; s > 0; s >>= 1) {
        if (tid < s) { sh[tid] += sh[tid + s]; sh[256 + tid] += sh[256 + tid + s]; }
        __syncthreads();
    }
    if (tid == 0) { partials[2 * blk] = sh[0]; partials[2 * blk + 1] = sh[256]; }

    // ---- completion-counter fused final (parallel loads, fixed tree) ----
    __threadfence();
    __shared__ unsigned done;
    if (tid == 0) done = atomicAdd(counter, 1u);
    __syncthreads();
    if (done == 127) {
        __shared__ double sv[128], cv[128];
        if (tid < 128) {   // parallel loads: one memory round trip
            sv[tid] = __hip_atomic_load(&partials[2 * tid],
                                        __ATOMIC_ACQUIRE, __HIP_MEMORY_SCOPE_AGENT);
            cv[tid] = __hip_atomic_load(&partials[2 * tid + 1],
                                        __ATOMIC_ACQUIRE, __HIP_MEMORY_SCOPE_AGENT);
        }
        __syncthreads();
        // fixed tree within each batch's 32 entries -> deterministic
        for (int s = 16; s > 0; s >>= 1) {
            if (tid < 128 && (tid & 31) < s) {
                sv[tid] += sv[tid + s];
                cv[tid] += cv[tid + s];
            }
            __syncthreads();
        }
        if (tid == 0) {
            double acc = 0.0;
            for (int b = 0; b < 4; ++b) {
                double c = cv[32 * b] > 1.0 ? cv[32 * b] : 1.0;
                acc += sv[32 * b] / (3.0 * c);
            }
            out[0] = (float)(acc * 0.25);
        }
    }
}

extern "C" void kernel_launch(void* const* d_in, const int* in_sizes, int n_in,
                              void* d_out, int out_size, void* d_ws, size_t ws_size,
                              hipStream_t stream) {
    const float* src = (const float*)d_in[0];
    const float* tgt = (const float*)d_in[1];
    float* out = (float*)d_out;

    // ws: Apk 1MB | Bpk 1MB | wspart 1MB | partials 2KB | counter
    unsigned short* Apk = (unsigned short*)d_ws;
    unsigned short* Bpk = (unsigned short*)((char*)d_ws + (1u << 20));
    float* wspart       = (float*)((char*)d_ws + (2u << 20));
    double* partials    = (double*)((char*)d_ws + (3u << 20));
    unsigned* counter   = (unsigned*)((char*)d_ws + (3u << 20) + 4096);

    prep_kernel<<<dim3(BN / 256), dim3(256), 0, stream>>>(src, tgt, Apk, Bpk, counter);
    nn_mfma_kernel<<<dim3(SGRP, NCHUNK, NBATCH), dim3(256), 0, stream>>>(Apk, Bpk, wspart);
    reduce_kernel<<<dim3(BN / 256), dim3(256), 0, stream>>>(src, wspart, partials, counter, out);
}

// Round 18
// 23.335 us; speedup vs baseline: 1.6371x; 1.6371x over previous
//
#include <hip/hip_runtime.h>

// Fixed-shape problem
#define NBATCH 4
#define NPTS   8192
#define MTGT   8192
#define BN     (NBATCH*NPTS)      // 32768 sources (== total targets)
#define NCHUNK 8                  // target chunks per batch (1024 targets each)
#define SGRP   32                 // source groups per batch (256 sources each)
// grid: (32, 8, 4) = 1024 blocks of 256 threads (4 waves)

typedef __attribute__((ext_vector_type(8)))  short bf16x8;   // guide-verified frag type
typedef __attribute__((ext_vector_type(16))) float f32x16;

__device__ __forceinline__ unsigned short f2bf(float x) {   // RNE fp32->bf16
    unsigned u = __float_as_uint(x);
    return (unsigned short)((u + 0x7fffu + ((u >> 16) & 1u)) >> 16);
}
__device__ __forceinline__ float bf2f(unsigned short h) {
    return __uint_as_float(((unsigned)h) << 16);
}

// Pack A (sources, scaled by -2, hi/lo split) and B (targets hi/lo + ||t||^2
// 3-way split) into MFMA fragment order (slot pairing validated: R13-R17
// absmax 0.0).
__global__ __launch_bounds__(256) void prep_kernel(const float* __restrict__ src,
                                                   const float* __restrict__ tgt,
                                                   unsigned short* __restrict__ Apk,
                                                   unsigned short* __restrict__ Bpk) {
    const int i = blockIdx.x * 256 + threadIdx.x;   // 0..BN-1
    const int T = i >> 5, l = i & 31;
    const unsigned ONE = 0x3F80u;

    // ---- A: a = -2*s
    float sx = src[3*(size_t)i], sy = src[3*(size_t)i+1], sz = src[3*(size_t)i+2];
    float axf = -2.f*sx, ayf = -2.f*sy, azf = -2.f*sz;
    unsigned axh = f2bf(axf), ayh = f2bf(ayf), azh = f2bf(azf);
    unsigned axl = f2bf(axf - bf2f(axh));
    unsigned ayl = f2bf(ayf - bf2f(ayh));
    unsigned azl = f2bf(azf - bf2f(azh));
    uint4* a0 = (uint4*)(Apk + ((size_t)T*64 +      l) * 8);
    uint4* a1 = (uint4*)(Apk + ((size_t)T*64 + 32 + l) * 8);
    *a0 = make_uint4(axh | (ayh<<16), azh | (axl<<16), ayl | (azl<<16), axh | (ayh<<16));
    *a1 = make_uint4(azh | (ONE<<16), ONE | (ONE<<16), 0u, 0u);

    // ---- B: t hi/lo + tsq 3-split (invalid target -> tsq = 1e30)
    float tx = tgt[3*(size_t)i], ty = tgt[3*(size_t)i+1], tz = tgt[3*(size_t)i+2];
    unsigned txh = f2bf(tx), tyh = f2bf(ty), tzh = f2bf(tz);
    unsigned txl = f2bf(tx - bf2f(txh));
    unsigned tyl = f2bf(ty - bf2f(tyh));
    unsigned tzl = f2bf(tz - bf2f(tzh));
    float tsq = fmaf(tx, tx, fmaf(ty, ty, tz * tz));
    bool valid = (tx != 0.f) || (ty != 0.f) || (tz != 0.f);
    unsigned qh, qm, ql;
    if (valid) {
        qh = f2bf(tsq);
        float r1 = tsq - bf2f(qh); qm = f2bf(r1);
        float r2 = r1 - bf2f(qm);  ql = f2bf(r2);
    } else { qh = f2bf(1e30f); qm = 0u; ql = 0u; }
    uint4* b0 = (uint4*)(Bpk + ((size_t)T*64 +      l) * 8);
    uint4* b1 = (uint4*)(Bpk + ((size_t)T*64 + 32 + l) * 8);
    *b0 = make_uint4(txh | (tyh<<16), tzh | (txh<<16), tyh | (tzh<<16), txl | (tyl<<16));
    *b1 = make_uint4(tzl | (qh<<16), qm | (ql<<16), 0u, 0u);
}

// min over the 16 C-regs + accumulator: 8 v_min3-fusable ops, exact/associative.
__device__ __forceinline__ float min16(const f32x16& d, float acc) {
    float r0 = fminf(fminf(d[0],  d[1]),  d[2]);
    float r1 = fminf(fminf(d[3],  d[4]),  d[5]);
    float r2 = fminf(fminf(d[6],  d[7]),  d[8]);
    float r3 = fminf(fminf(d[9],  d[10]), d[11]);
    float r4 = fminf(fminf(d[12], d[13]), d[14]);
    float s0 = fminf(fminf(r0, r1), r2);
    float s1 = fminf(fminf(r3, r4), d[15]);
    return fminf(fminf(s0, s1), acc);
}

// OPERAND-SWAPPED nn kernel (R16's exact kernel, validated absmax 0.0):
// rows = targets, cols = sources. Min over targets = in-lane min16 trees +
// ONE shfl_xor(32) per strip -- no 160-bpermute epilogue (the R14 tax).
__global__ __launch_bounds__(256, 4) void nn_mfma_kernel(const unsigned short* __restrict__ Apk,
                                                         const unsigned short* __restrict__ Bpk,
                                                         float* __restrict__ wspart) {
    const int lane = threadIdx.x & 63, wid = threadIdx.x >> 6;
    const int sg = blockIdx.x, cy = blockIdx.y, bz = blockIdx.z;

    const bf16x8* Ap = (const bf16x8*)Apk;
    const bf16x8* Bp = (const bf16x8*)Bpk;

    const int Ts0 = bz * 256 + sg * 8 + wid * 2;      // 2 source strips (cols)
    bf16x8 s0 = Ap[(size_t)Ts0 * 64 + lane];
    bf16x8 s1 = Ap[(size_t)(Ts0 + 1) * 64 + lane];

    f32x16 z;
#pragma unroll
    for (int e = 0; e < 16; ++e) z[e] = 0.f;
    float acc0 = 3e38f, acc1 = 3e38f;

    const int Tb0 = bz * 256 + cy * 32;               // 32 target tiles (rows)
    const bf16x8* bp = Bp + (size_t)Tb0 * 64 + lane;

#pragma unroll 2
    for (int m = 0; m < 32; m += 2) {
        bf16x8 tfA = bp[(size_t)m * 64];              // 16B/lane coalesced, L1-shared
        bf16x8 tfB = bp[(size_t)(m + 1) * 64];
        f32x16 d0 = __builtin_amdgcn_mfma_f32_32x32x16_bf16(tfA, s0, z, 0, 0, 0);
        f32x16 d1 = __builtin_amdgcn_mfma_f32_32x32x16_bf16(tfA, s1, z, 0, 0, 0);
        f32x16 d2 = __builtin_amdgcn_mfma_f32_32x32x16_bf16(tfB, s0, z, 0, 0, 0);
        f32x16 d3 = __builtin_amdgcn_mfma_f32_32x32x16_bf16(tfB, s1, z, 0, 0, 0);
        acc0 = min16(d0, acc0);
        acc1 = min16(d1, acc1);
        acc0 = min16(d2, acc0);
        acc1 = min16(d3, acc1);
    }

    // combine lane-halves (complementary target rows) -- one swap per strip
    float f0 = fminf(acc0, __shfl_xor(acc0, 32));
    float f1 = fminf(acc1, __shfl_xor(acc1, 32));

    // lane = source col -> coalesced 128B stores from lanes 0..31
    if (lane < 32) {
        float* wb = wspart + (size_t)cy * BN + (size_t)bz * NPTS + sg * 256 + wid * 64;
        wb[lane]      = f0;
        wb[32 + lane] = f1;
    }
}

// 128 blocks x 256: min over 8 chunk-partials (coalesced), + ||s||^2, validity,
// fixed-order double partials -> bit-deterministic. (R14's plain version:
// no counter, no threadfence -- the fused final cost ~9.5us, R17.)
__global__ __launch_bounds__(256) void reduce_kernel(const float* __restrict__ src,
                                                     const float* __restrict__ wspart,
                                                     double* __restrict__ partials) {
    const int blk = blockIdx.x, tid = threadIdx.x;
    const int gid = blk * 256 + tid;

    float m = 3e38f;
#pragma unroll
    for (int c = 0; c < NCHUNK; ++c) m = fminf(m, wspart[(size_t)c * BN + gid]);

    float sx = src[3*(size_t)gid], sy = src[3*(size_t)gid+1], sz = src[3*(size_t)gid+2];
    bool valid = (sx != 0.f) || (sy != 0.f) || (sz != 0.f);
    float ssq = fmaf(sx, sx, fmaf(sy, sy, sz * sz));
    float sq = fmaxf(0.f, ssq + m);

    __shared__ double sh[512];
    sh[tid] = valid ? (double)sq : 0.0;
    sh[256 + tid] = valid ? 1.0 : 0.0;
    __syncthreads();
    for (int s = 128; s > 0; s >>= 1) {
        if (tid < s) { sh[tid] += sh[tid + s]; sh[256 + tid] += sh[256 + tid + s]; }
        __syncthreads();
    }
    if (tid == 0) { partials[2 * blk] = sh[0]; partials[2 * blk + 1] = sh[256]; }
}

// Fixed-order final combine (batch t owns partial blocks 32t..32t+31).
__global__ void final_kernel(const double* __restrict__ partials, float* __restrict__ out) {
    __shared__ double bmv[4];
    int t = threadIdx.x;
    if (t < 4) {
        double s = 0.0, c = 0.0;
        for (int i = 0; i < 32; ++i) {
            s += partials[2 * (t * 32 + i)];
            c += partials[2 * (t * 32 + i) + 1];
        }
        if (c < 1.0) c = 1.0;
        bmv[t] = s / (3.0 * c);
    }
    __syncthreads();
    if (t == 0) out[0] = (float)((bmv[0] + bmv[1] + bmv[2] + bmv[3]) * 0.25);
}

extern "C" void kernel_launch(void* const* d_in, const int* in_sizes, int n_in,
                              void* d_out, int out_size, void* d_ws, size_t ws_size,
                              hipStream_t stream) {
    const float* src = (const float*)d_in[0];
    const float* tgt = (const float*)d_in[1];
    float* out = (float*)d_out;

    // ws: Apk 1MB | Bpk 1MB | wspart 1MB | partials 2KB
    unsigned short* Apk = (unsigned short*)d_ws;
    unsigned short* Bpk = (unsigned short*)((char*)d_ws + (1u << 20));
    float* wspart       = (float*)((char*)d_ws + (2u << 20));
    double* partials    = (double*)((char*)d_ws + (3u << 20));

    prep_kernel<<<dim3(BN / 256), dim3(256), 0, stream>>>(src, tgt, Apk, Bpk);
    nn_mfma_kernel<<<dim3(SGRP, NCHUNK, NBATCH), dim3(256), 0, stream>>>(Apk, Bpk, wspart);
    reduce_kernel<<<dim3(BN / 256), dim3(256), 0, stream>>>(src, wspart, partials);
    final_kernel<<<dim3(1), dim3(64), 0, stream>>>(partials, out);
}